// Round 1
// baseline (566.804 us; speedup 1.0000x reference)
//
#include <hip/hip_runtime.h>
#include <stdint.h>

#define HID 128
#define BPB 8  // batch elements (waves) per block; block = 512 threads

__global__ __launch_bounds__(512, 4) void lsnn_fwd(
    const float* __restrict__ x,      // (B,4)
    const float* __restrict__ w_in,   // (128,8)
    const float* __restrict__ w_rec,  // (128,128)
    const float* __restrict__ w_out,  // (2,128)
    float* __restrict__ out,          // (B,2)
    int B)
{
#pragma clang fp contract(off)
  // w_rec rows, XOR-swizzled on 16B granules: row r, logical group g (k=4g..4g+3)
  // stored at slot (g ^ (r&31)). Read back with the same XOR -> conflict-free.
  __shared__ float wrec_s[HID * HID];

  const int tid = threadIdx.x;
  for (int q = tid; q < HID * 32; q += 512) {
    int row = q >> 5;
    int g = q & 31;
    float4 v = reinterpret_cast<const float4*>(w_rec)[q];
    reinterpret_cast<float4*>(wrec_s)[(row << 5) | (g ^ (row & 31))] = v;
  }
  __syncthreads();

  const int lane = tid & 63;
  const int b = blockIdx.x * BPB + (tid >> 6);
  if (b >= B) return;

  const int j0 = lane;
  const int j1 = lane + 64;

  // ---------- encoder: 8 channels (4 pos, 4 neg), pack spike bits ----------
  float cc[8], ev[8];
  {
    float xv0 = x[b * 4 + 0], xv1 = x[b * 4 + 1];
    float xv2 = x[b * 4 + 2], xv3 = x[b * 4 + 3];
    cc[0] = fmaxf(50.0f * xv0, 0.0f);
    cc[1] = fmaxf(50.0f * xv1, 0.0f);
    cc[2] = fmaxf(50.0f * xv2, 0.0f);
    cc[3] = fmaxf(50.0f * xv3, 0.0f);
    cc[4] = fmaxf(-50.0f * xv0, 0.0f);
    cc[5] = fmaxf(-50.0f * xv1, 0.0f);
    cc[6] = fmaxf(-50.0f * xv2, 0.0f);
    cc[7] = fmaxf(-50.0f * xv3, 0.0f);
  }
#pragma unroll
  for (int c = 0; c < 8; ++c) ev[c] = 0.0f;

  uint64_t pk[5];  // 40 steps x 8 channel-bits, byte per step
#pragma unroll
  for (int tw = 0; tw < 5; ++tw) {
    uint64_t pw = 0;
    for (int ts = 0; ts < 8; ++ts) {
      unsigned byte = 0;
#pragma unroll
      for (int c = 0; c < 8; ++c) {
        ev[c] = ev[c] + 0.1f * (cc[c] - ev[c]);
        if (ev[c] - 1.0f > 0.0f) {
          byte |= (1u << c);
          ev[c] = 0.0f;
        }
      }
      pw |= ((uint64_t)byte) << (ts << 3);
    }
    pk[tw] = pw;
  }

  // ---------- per-unit weights in registers ----------
  float win0[8], win1[8];
#pragma unroll
  for (int c = 0; c < 8; ++c) {
    win0[c] = w_in[j0 * 8 + c];
    win1[c] = w_in[j1 * 8 + c];
  }
  const float wo00 = w_out[j0], wo01 = w_out[j1];
  const float wo10 = w_out[HID + j0], wo11 = w_out[HID + j1];

  // ---------- state ----------
  float v0 = 0.f, v1 = 0.f, i0 = 0.f, i1 = 0.f, b0 = 1.0f, b1 = 1.0f;
  float io0 = 0.f, io1 = 0.f, vo0 = 0.f, vo1 = 0.f;
  float mm0 = -INFINITY, mm1 = -INFINITY;
  uint64_t zm0 = 0ull, zm1 = 0ull;

  const int bx0 = (j0 << 9) ^ ((lane & 31) << 4);
  const int bx1 = (j1 << 9) ^ ((lane & 31) << 4);
  const char* wb = (const char*)wrec_s;

  // ---------- T=40 recurrent steps (5 words x 8 steps, static pk index) ----------
#pragma unroll
  for (int tw = 0; tw < 5; ++tw) {
    uint64_t pw = pk[tw];
    for (int ts = 0; ts < 8; ++ts) {
      float vd0 = v0 + 0.1f * (i0 - v0);
      float vd1 = v1 + 0.1f * (i1 - v1);
      float id0 = i0 - 0.2f * i0;
      float id1 = i1 - 0.2f * i1;
      float bd0 = b0 + 1.4285714285714286e-06f * (1.0f - b0);
      float bd1 = b1 + 1.4285714285714286e-06f * (1.0f - b1);
      bool z0 = (vd0 - bd0) > 0.0f;
      bool z1 = (vd1 - bd1) > 0.0f;
      v0 = z0 ? 0.0f : vd0;
      v1 = z1 ? 0.0f : vd1;
      b0 = bd0 + (z0 ? 0.0025714285714285714f : 0.0f);
      b1 = bd1 + (z1 ? 0.0025714285714285714f : 0.0f);

      // readout projection of z_new: 2-scalar butterfly reduce over the wave
      float p0 = (z0 ? wo00 : 0.0f) + (z1 ? wo01 : 0.0f);
      float p1 = (z0 ? wo10 : 0.0f) + (z1 ? wo11 : 0.0f);
#pragma unroll
      for (int s = 1; s < 64; s <<= 1) {
        p0 += __shfl_xor(p0, s);
        p1 += __shfl_xor(p1, s);
      }

      // LI readout (vo uses OLD io), track running max
      float von0 = vo0 + 0.1f * (io0 - vo0);
      float von1 = vo1 + 0.1f * (io1 - vo1);
      io0 = (io0 - 0.2f * io0) + p0;
      io1 = (io1 - 0.2f * io1) + p1;
      vo0 = von0;
      vo1 = von1;
      mm0 = fmaxf(mm0, von0);
      mm1 = fmaxf(mm1, von1);

      // input current from encoder spikes (byte is wave-uniform)
      int xb = (int)((pw >> (ts << 3)) & 0xFF);
      float ai0 = 0.f, ai1 = 0.f;
#pragma unroll
      for (int c = 0; c < 8; ++c) {
        if (xb & (1 << c)) {
          ai0 += win0[c];
          ai1 += win1[c];
        }
      }

      // recurrent current from OLD z (zm* live in SGPRs -> uniform nibble skip)
      float ar0 = 0.f, ar1 = 0.f;
#pragma unroll
      for (int hh = 0; hh < 2; ++hh) {
        uint64_t mask = hh ? zm1 : zm0;
        if (mask) {
#pragma unroll
          for (int q = 0; q < 16; ++q) {
            int nib = ((int)(mask >> (q << 2))) & 0xF;
            if (nib) {
              int goff = (hh << 8) | (q << 4);
              float4 w0 = *(const float4*)(wb + (bx0 ^ goff));
              float4 w1 = *(const float4*)(wb + (bx1 ^ goff));
              if (nib & 1) { ar0 += w0.x; ar1 += w1.x; }
              if (nib & 2) { ar0 += w0.y; ar1 += w1.y; }
              if (nib & 4) { ar0 += w0.z; ar1 += w1.z; }
              if (nib & 8) { ar0 += w0.w; ar1 += w1.w; }
            }
          }
        }
      }

      i0 = (id0 + ai0) + ar0;
      i1 = (id1 + ai1) + ar1;

      zm0 = __ballot(z0);
      zm1 = __ballot(z1);
    }
  }

  // ---------- softmax over the 2 per-batch max-voltages ----------
  if (lane == 0) {
    float mx = fmaxf(mm0, mm1);
    float e0 = expf(mm0 - mx);
    float e1 = expf(mm1 - mx);
    float s = e0 + e1;
    out[b * 2 + 0] = e0 / s;
    out[b * 2 + 1] = e1 / s;
  }
}

extern "C" void kernel_launch(void* const* d_in, const int* in_sizes, int n_in,
                              void* d_out, int out_size, void* d_ws, size_t ws_size,
                              hipStream_t stream) {
  (void)n_in; (void)out_size; (void)d_ws; (void)ws_size;
  const float* x = (const float*)d_in[0];
  const float* w_in = (const float*)d_in[1];
  const float* w_rec = (const float*)d_in[2];
  const float* w_out = (const float*)d_in[3];
  float* out = (float*)d_out;
  int B = in_sizes[0] / 4;
  int blocks = (B + BPB - 1) / BPB;
  lsnn_fwd<<<blocks, 512, 0, stream>>>(x, w_in, w_rec, w_out, out, B);
}

// Round 2
// 202.883 us; speedup vs baseline: 2.7938x; 2.7938x over previous
//
#include <hip/hip_runtime.h>
#include <stdint.h>

#define HID 128
#define BPB 16  // batch elements (waves) per block; block = 1024 threads

// Full-wave64 f32 sum via DPP (VALU pipe, no LDS). Totals land in lane 63.
__device__ __forceinline__ void wave_reduce_add2(float& a, float& b) {
  asm("v_add_f32 %0, %0, %0 row_shr:1 bound_ctrl:0\n\t"
      "v_add_f32 %1, %1, %1 row_shr:1 bound_ctrl:0\n\t"
      "v_add_f32 %0, %0, %0 row_shr:2 bound_ctrl:0\n\t"
      "v_add_f32 %1, %1, %1 row_shr:2 bound_ctrl:0\n\t"
      "v_add_f32 %0, %0, %0 row_shr:4 bound_ctrl:0\n\t"
      "v_add_f32 %1, %1, %1 row_shr:4 bound_ctrl:0\n\t"
      "v_add_f32 %0, %0, %0 row_shr:8 bound_ctrl:0\n\t"
      "v_add_f32 %1, %1, %1 row_shr:8 bound_ctrl:0\n\t"
      "v_add_f32 %0, %0, %0 row_bcast:15 row_mask:0xa\n\t"
      "v_add_f32 %1, %1, %1 row_bcast:15 row_mask:0xa\n\t"
      "v_add_f32 %0, %0, %0 row_bcast:31 row_mask:0xc\n\t"
      "v_add_f32 %1, %1, %1 row_bcast:31 row_mask:0xc\n\t"
      : "+v"(a), "+v"(b));
}

__global__ __launch_bounds__(1024, 8) void lsnn_fwd(
    const float* __restrict__ x,      // (B,4)
    const float* __restrict__ w_in,   // (128,8)
    const float* __restrict__ w_rec,  // (128,128)
    const float* __restrict__ w_out,  // (2,128)
    float* __restrict__ out,          // (B,2)
    int B)
{
#pragma clang fp contract(off)
  // Transposed recurrent weights: wt[k][l'] = (w_rec[l][k], w_rec[l+64][k])
  // with l' = l ^ (k & 63). Per spiking k (uniform), lanes read contiguous
  // (permuted) float2 -> conflict-free ds_read_b64. 64 KiB.
  __shared__ float2 wt[HID * 64];

  const int tid = threadIdx.x;
#pragma unroll
  for (int m = 0; m < 8; ++m) {
    int idx = m * 1024 + tid;
    int k = idx & 127;        // presynaptic index (coalesced fast axis)
    int l = idx >> 7;         // postsynaptic pair index 0..63
    float a = w_rec[l * HID + k];
    float c = w_rec[(l + 64) * HID + k];
    wt[(k << 6) | (l ^ (k & 63))] = make_float2(a, c);
  }
  __syncthreads();

  const int lane = tid & 63;
  const int b = blockIdx.x * BPB + (tid >> 6);
  if (b >= B) return;

  const int j0 = lane;
  const int j1 = lane + 64;

  // ---------- encoder: 8 channels (4 pos, 4 neg), pack spike bits ----------
  float cc[8], ev[8];
  {
    float xv0 = x[b * 4 + 0], xv1 = x[b * 4 + 1];
    float xv2 = x[b * 4 + 2], xv3 = x[b * 4 + 3];
    cc[0] = fmaxf(50.0f * xv0, 0.0f);
    cc[1] = fmaxf(50.0f * xv1, 0.0f);
    cc[2] = fmaxf(50.0f * xv2, 0.0f);
    cc[3] = fmaxf(50.0f * xv3, 0.0f);
    cc[4] = fmaxf(-50.0f * xv0, 0.0f);
    cc[5] = fmaxf(-50.0f * xv1, 0.0f);
    cc[6] = fmaxf(-50.0f * xv2, 0.0f);
    cc[7] = fmaxf(-50.0f * xv3, 0.0f);
  }
#pragma unroll
  for (int c = 0; c < 8; ++c) ev[c] = 0.0f;

  uint64_t pk[5];  // 40 steps x 8 channel-bits, one byte per step
#pragma unroll
  for (int tw = 0; tw < 5; ++tw) {
    uint64_t pw = 0;
    for (int ts = 0; ts < 8; ++ts) {
      unsigned byte = 0;
#pragma unroll
      for (int c = 0; c < 8; ++c) {
        ev[c] = ev[c] + 0.1f * (cc[c] - ev[c]);
        if (ev[c] - 1.0f > 0.0f) {
          byte |= (1u << c);
          ev[c] = 0.0f;
        }
      }
      pw |= ((uint64_t)byte) << (ts << 3);
    }
    pk[tw] = pw;
  }

  // ---------- per-unit weights in registers ----------
  float win0[8], win1[8];
#pragma unroll
  for (int c = 0; c < 8; ++c) {
    win0[c] = w_in[j0 * 8 + c];
    win1[c] = w_in[j1 * 8 + c];
  }
  const float wo00 = w_out[j0], wo01 = w_out[j1];
  const float wo10 = w_out[HID + j0], wo11 = w_out[HID + j1];

  // ---------- state ----------
  float v0 = 0.f, v1 = 0.f, i0 = 0.f, i1 = 0.f, b0 = 1.0f, b1 = 1.0f;
  float io0 = 0.f, io1 = 0.f, vo0 = 0.f, vo1 = 0.f;
  float mm0 = -INFINITY, mm1 = -INFINITY;
  uint64_t zm0 = 0ull, zm1 = 0ull;

  const char* wtb = (const char*)wt;
  const int vb = lane << 3;  // per-lane float2 base; XOR'ed with scalar k-offset

  // ---------- T=40 recurrent steps (5 words x 8 steps, static pk index) ----------
#pragma unroll
  for (int tw = 0; tw < 5; ++tw) {
    uint64_t pw = pk[tw];
    for (int ts = 0; ts < 8; ++ts) {
      float vd0 = v0 + 0.1f * (i0 - v0);
      float vd1 = v1 + 0.1f * (i1 - v1);
      float id0 = i0 - 0.2f * i0;
      float id1 = i1 - 0.2f * i1;
      float bd0 = b0 + 1.4285714285714286e-06f * (1.0f - b0);
      float bd1 = b1 + 1.4285714285714286e-06f * (1.0f - b1);
      bool z0 = (vd0 - bd0) > 0.0f;
      bool z1 = (vd1 - bd1) > 0.0f;
      v0 = z0 ? 0.0f : vd0;
      v1 = z1 ? 0.0f : vd1;
      b0 = bd0 + (z0 ? 0.0025714285714285714f : 0.0f);
      b1 = bd1 + (z1 ? 0.0025714285714285714f : 0.0f);

      // readout projection of z_new: DPP wave-reduce (valid in lane 63 only)
      float p0 = (z0 ? wo00 : 0.0f) + (z1 ? wo01 : 0.0f);
      float p1 = (z0 ? wo10 : 0.0f) + (z1 ? wo11 : 0.0f);
      wave_reduce_add2(p0, p1);

      // LI readout (vo uses OLD io), running max — valid in lane 63 only
      float von0 = vo0 + 0.1f * (io0 - vo0);
      float von1 = vo1 + 0.1f * (io1 - vo1);
      io0 = (io0 - 0.2f * io0) + p0;
      io1 = (io1 - 0.2f * io1) + p1;
      vo0 = von0;
      vo1 = von1;
      mm0 = fmaxf(mm0, von0);
      mm1 = fmaxf(mm1, von1);

      // input current from encoder spikes (byte identical across lanes)
      int xb = (int)((pw >> (ts << 3)) & 0xFF);
      float ai0 = 0.f, ai1 = 0.f;
#pragma unroll
      for (int c = 0; c < 8; ++c) {
        if (xb & (1 << c)) {
          ai0 += win0[c];
          ai1 += win1[c];
        }
      }

      // recurrent current from OLD z: one conflict-free ds_read_b64 per
      // spiking k, iterated via uniform scalar find-first-set (ascending k,
      // preserving the reference accumulation order)
      float ar0 = 0.f, ar1 = 0.f;
      uint64_t m0 = zm0;
      while (m0) {
        int k = __builtin_ctzll(m0);
        m0 &= m0 - 1;
        int soff = k * 520;  // (k<<9)|(k<<3), disjoint bit fields
        float2 w = *(const float2*)(wtb + (vb ^ soff));
        ar0 += w.x;
        ar1 += w.y;
      }
      uint64_t m1 = zm1;
      while (m1) {
        int k = __builtin_ctzll(m1);
        m1 &= m1 - 1;
        int soff = 32768 + k * 520;  // ((64+k)<<9)|(k<<3)
        float2 w = *(const float2*)(wtb + (vb ^ soff));
        ar0 += w.x;
        ar1 += w.y;
      }

      i0 = (id0 + ai0) + ar0;
      i1 = (id1 + ai1) + ar1;

      zm0 = __ballot(z0);
      zm1 = __ballot(z1);
    }
  }

  // ---------- softmax over the 2 per-batch max-voltages (lane 63 valid) ----
  if (lane == 63) {
    float mx = fmaxf(mm0, mm1);
    float e0 = expf(mm0 - mx);
    float e1 = expf(mm1 - mx);
    float s = e0 + e1;
    out[b * 2 + 0] = e0 / s;
    out[b * 2 + 1] = e1 / s;
  }
}

extern "C" void kernel_launch(void* const* d_in, const int* in_sizes, int n_in,
                              void* d_out, int out_size, void* d_ws, size_t ws_size,
                              hipStream_t stream) {
  (void)n_in; (void)out_size; (void)d_ws; (void)ws_size;
  const float* x = (const float*)d_in[0];
  const float* w_in = (const float*)d_in[1];
  const float* w_rec = (const float*)d_in[2];
  const float* w_out = (const float*)d_in[3];
  float* out = (float*)d_out;
  int B = in_sizes[0] / 4;
  int blocks = (B + BPB - 1) / BPB;
  lsnn_fwd<<<blocks, 1024, 0, stream>>>(x, w_in, w_rec, w_out, out, B);
}

// Round 3
// 146.593 us; speedup vs baseline: 3.8665x; 1.3840x over previous
//
#include <hip/hip_runtime.h>
#include <stdint.h>

#define HID 128
#define BPB 16  // batch elements (waves) per block; block = 1024 threads

// Full-wave64 f32 sum via DPP (VALU pipe, no LDS). Totals land in lane 63.
__device__ __forceinline__ void wave_reduce_add2(float& a, float& b) {
  asm("v_add_f32 %0, %0, %0 row_shr:1 bound_ctrl:0\n\t"
      "v_add_f32 %1, %1, %1 row_shr:1 bound_ctrl:0\n\t"
      "v_add_f32 %0, %0, %0 row_shr:2 bound_ctrl:0\n\t"
      "v_add_f32 %1, %1, %1 row_shr:2 bound_ctrl:0\n\t"
      "v_add_f32 %0, %0, %0 row_shr:4 bound_ctrl:0\n\t"
      "v_add_f32 %1, %1, %1 row_shr:4 bound_ctrl:0\n\t"
      "v_add_f32 %0, %0, %0 row_shr:8 bound_ctrl:0\n\t"
      "v_add_f32 %1, %1, %1 row_shr:8 bound_ctrl:0\n\t"
      "v_add_f32 %0, %0, %0 row_bcast:15 row_mask:0xa\n\t"
      "v_add_f32 %1, %1, %1 row_bcast:15 row_mask:0xa\n\t"
      "v_add_f32 %0, %0, %0 row_bcast:31 row_mask:0xc\n\t"
      "v_add_f32 %1, %1, %1 row_bcast:31 row_mask:0xc\n\t"
      : "+v"(a), "+v"(b));
}

__global__ __launch_bounds__(1024, 4) void lsnn_fwd(
    const float* __restrict__ x,      // (B,4)
    const float* __restrict__ w_in,   // (128,8)
    const float* __restrict__ w_rec,  // (128,128)
    const float* __restrict__ w_out,  // (2,128)
    float* __restrict__ out,          // (B,2)
    int B)
{
#pragma clang fp contract(off)
  // Transposed recurrent weights: wt[k][l'] = (w_rec[l][k], w_rec[l+64][k])
  // with l' = l ^ (k & 63). Per spiking k (uniform), lanes read contiguous
  // (permuted) float2 -> conflict-free ds_read_b64. 64 KiB.
  __shared__ float2 wt[HID * 64];

  const int tid = threadIdx.x;
#pragma unroll
  for (int m = 0; m < 8; ++m) {
    int idx = m * 1024 + tid;
    int k = idx & 127;        // presynaptic index (coalesced fast axis)
    int l = idx >> 7;         // postsynaptic pair index 0..63
    float a = w_rec[l * HID + k];
    float c = w_rec[(l + 64) * HID + k];
    wt[(k << 6) | (l ^ (k & 63))] = make_float2(a, c);
  }
  __syncthreads();

  const int lane = tid & 63;
  const int b = blockIdx.x * BPB + (tid >> 6);
  if (b >= B) return;

  const int j0 = lane;
  const int j1 = lane + 64;

  // ---------- encoder: 4 effective channels (pos/neg mutually exclusive) ---
  // For dim c: active channel current = |50*x_c| (bit-equal to relu of the
  // active side); the inactive side's current is exactly 0 -> never spikes.
  // Effective w_in column = pos column if x>0 else neg column.
  float cc[4], ev[4];
  float wsel0[4], wsel1[4];
  {
#pragma unroll
    for (int c = 0; c < 4; ++c) {
      float p = 50.0f * x[b * 4 + c];
      cc[c] = fabsf(p);
      ev[c] = 0.0f;
      int col = (p > 0.0f) ? c : (c + 4);
      wsel0[c] = w_in[j0 * 8 + col];
      wsel1[c] = w_in[j1 * 8 + col];
    }
  }

  uint64_t pk[5];  // 40 steps x 4 channel-bits, one byte per step
#pragma unroll
  for (int tw = 0; tw < 5; ++tw) {
    uint64_t pw = 0;
    for (int ts = 0; ts < 8; ++ts) {
      unsigned byte = 0;
#pragma unroll
      for (int c = 0; c < 4; ++c) {
        ev[c] = ev[c] + 0.1f * (cc[c] - ev[c]);
        if (ev[c] - 1.0f > 0.0f) {
          byte |= (1u << c);
          ev[c] = 0.0f;
        }
      }
      pw |= ((uint64_t)byte) << (ts << 3);
    }
    pk[tw] = pw;
  }

  const float wo00 = w_out[j0], wo01 = w_out[j1];
  const float wo10 = w_out[HID + j0], wo11 = w_out[HID + j1];

  // ---------- state ----------
  float v0 = 0.f, v1 = 0.f, i0 = 0.f, i1 = 0.f, b0 = 1.0f, b1 = 1.0f;
  float io0 = 0.f, io1 = 0.f, vo0 = 0.f, vo1 = 0.f;
  float mm0 = -INFINITY, mm1 = -INFINITY;
  uint64_t zm0 = 0ull, zm1 = 0ull;

  const char* wtb = (const char*)wt;
  const int vb = lane << 3;  // per-lane float2 base; XOR'ed with scalar k-offset

  // ---------- T=40 recurrent steps (5 words x 8 steps, static pk index) ----
#pragma unroll
  for (int tw = 0; tw < 5; ++tw) {
    uint64_t pw = pk[tw];
    for (int ts = 0; ts < 8; ++ts) {
      float vd0 = v0 + 0.1f * (i0 - v0);
      float vd1 = v1 + 0.1f * (i1 - v1);
      float id0 = i0 - 0.2f * i0;
      float id1 = i1 - 0.2f * i1;
      float bd0 = b0 + 1.4285714285714286e-06f * (1.0f - b0);
      float bd1 = b1 + 1.4285714285714286e-06f * (1.0f - b1);
      bool z0 = (vd0 - bd0) > 0.0f;
      bool z1 = (vd1 - bd1) > 0.0f;
      v0 = z0 ? 0.0f : vd0;
      v1 = z1 ? 0.0f : vd1;
      b0 = bd0 + (z0 ? 0.0025714285714285714f : 0.0f);
      b1 = bd1 + (z1 ? 0.0025714285714285714f : 0.0f);

      // readout projection of z_new: DPP wave-reduce (valid in lane 63 only)
      float p0 = (z0 ? wo00 : 0.0f) + (z1 ? wo01 : 0.0f);
      float p1 = (z0 ? wo10 : 0.0f) + (z1 ? wo11 : 0.0f);
      wave_reduce_add2(p0, p1);

      // LI readout (vo uses OLD io), running max — valid in lane 63 only
      float von0 = vo0 + 0.1f * (io0 - vo0);
      float von1 = vo1 + 0.1f * (io1 - vo1);
      io0 = (io0 - 0.2f * io0) + p0;
      io1 = (io1 - 0.2f * io1) + p1;
      vo0 = von0;
      vo1 = von1;
      mm0 = fmaxf(mm0, von0);
      mm1 = fmaxf(mm1, von1);

      // input current from encoder spikes (nibble identical across lanes)
      int xb = (int)((pw >> (ts << 3)) & 0xFF);
      float ai0 = 0.f, ai1 = 0.f;
#pragma unroll
      for (int c = 0; c < 4; ++c) {
        if (xb & (1 << c)) {
          ai0 += wsel0[c];
          ai1 += wsel1[c];
        }
      }

      // recurrent current from OLD z: one conflict-free ds_read_b64 per
      // spiking k, iterated via uniform scalar find-first-set (ascending k,
      // preserving the reference accumulation order)
      float ar0 = 0.f, ar1 = 0.f;
      uint64_t m0 = zm0;
      while (m0) {
        int k = __builtin_ctzll(m0);
        m0 &= m0 - 1;
        int soff = k * 520;  // (k<<9)|(k<<3), disjoint bit fields
        float2 w = *(const float2*)(wtb + (vb ^ soff));
        ar0 += w.x;
        ar1 += w.y;
      }
      uint64_t m1 = zm1;
      while (m1) {
        int k = __builtin_ctzll(m1);
        m1 &= m1 - 1;
        int soff = 32768 + k * 520;  // ((64+k)<<9)|(k<<3)
        float2 w = *(const float2*)(wtb + (vb ^ soff));
        ar0 += w.x;
        ar1 += w.y;
      }

      i0 = (id0 + ai0) + ar0;
      i1 = (id1 + ai1) + ar1;

      zm0 = __ballot(z0);
      zm1 = __ballot(z1);
    }
  }

  // ---------- softmax over the 2 per-batch max-voltages (lane 63 valid) ----
  if (lane == 63) {
    float mx = fmaxf(mm0, mm1);
    float e0 = expf(mm0 - mx);
    float e1 = expf(mm1 - mx);
    float s = e0 + e1;
    out[b * 2 + 0] = e0 / s;
    out[b * 2 + 1] = e1 / s;
  }
}

extern "C" void kernel_launch(void* const* d_in, const int* in_sizes, int n_in,
                              void* d_out, int out_size, void* d_ws, size_t ws_size,
                              hipStream_t stream) {
  (void)n_in; (void)out_size; (void)d_ws; (void)ws_size;
  const float* x = (const float*)d_in[0];
  const float* w_in = (const float*)d_in[1];
  const float* w_rec = (const float*)d_in[2];
  const float* w_out = (const float*)d_in[3];
  float* out = (float*)d_out;
  int B = in_sizes[0] / 4;
  int blocks = (B + BPB - 1) / BPB;
  lsnn_fwd<<<blocks, 1024, 0, stream>>>(x, w_in, w_rec, w_out, out, B);
}